// Round 18
// baseline (163.040 us; speedup 1.0000x reference)
//
#include <hip/hip_runtime.h>

#define MAXDEG 64
#define CHUNK 3072
#define NBMAX 256   // buckets = ceil(N/512); N<=131072 (src must fit 17 bits)
#define BCAP 10240  // per-bucket ebuf capacity (mean 8192, sd ~90 -> +22 sigma)
#define NL 96       // k_l2 nodes per block (grid ~1042 -> 32 waves/CU)

typedef unsigned short u16;
typedef __attribute__((ext_vector_type(8))) short bf16x8;
typedef __attribute__((ext_vector_type(4))) float f32x4;

__device__ __forceinline__ u16 f2b(float f) {   // fp32 -> bf16 rne
    unsigned u = __float_as_uint(f);
    u += 0x7fffu + ((u >> 16) & 1u);
    return (u16)(u >> 16);
}

// Split 8 fp32 -> bf16x8 hi (truncate) + bf16x8 lo (trunc of exact remainder).
__device__ __forceinline__ void split8(const float* v, bf16x8& hi, bf16x8& lo) {
    unsigned hw[4], lw[4];
#pragma unroll
    for (int p = 0; p < 4; ++p) {
        unsigned u0 = __float_as_uint(v[2 * p]);
        unsigned u1 = __float_as_uint(v[2 * p + 1]);
        float l0 = v[2 * p]     - __uint_as_float(u0 & 0xffff0000u);
        float l1 = v[2 * p + 1] - __uint_as_float(u1 & 0xffff0000u);
        hw[p] = (u0 >> 16) | (u1 & 0xffff0000u);
        lw[p] = (__float_as_uint(l0) >> 16) | (__float_as_uint(l1) & 0xffff0000u);
    }
    hi = *reinterpret_cast<bf16x8*>(hw);
    lo = *reinterpret_cast<bf16x8*>(lw);
}

// acc(2x float4) += 8 packed bf16 (uint4)
__device__ __forceinline__ void bacc8(float4& a0, float4& a1, uint4 w) {
    a0.x += __uint_as_float(w.x << 16);
    a0.y += __uint_as_float(w.x & 0xffff0000u);
    a0.z += __uint_as_float(w.y << 16);
    a0.w += __uint_as_float(w.y & 0xffff0000u);
    a1.x += __uint_as_float(w.z << 16);
    a1.y += __uint_as_float(w.z & 0xffff0000u);
    a1.z += __uint_as_float(w.w << 16);
    a1.w += __uint_as_float(w.w & 0xffff0000u);
}

// unpack 8 packed bf16 -> 2x float4
__device__ __forceinline__ void b2f8(uint4 w, float4& r0, float4& r1) {
    r0.x = __uint_as_float(w.x << 16);
    r0.y = __uint_as_float(w.x & 0xffff0000u);
    r0.z = __uint_as_float(w.y << 16);
    r0.w = __uint_as_float(w.y & 0xffff0000u);
    r1.x = __uint_as_float(w.z << 16);
    r1.y = __uint_as_float(w.z & 0xffff0000u);
    r1.z = __uint_as_float(w.w << 16);
    r1.w = __uint_as_float(w.w & 0xffff0000u);
}

// ---- init: bucket cursors to region bases; zero sentinel rows ----
__global__ void k_init(int* __restrict__ gcur, int NB,
                       u16* __restrict__ y, u16* __restrict__ y2, int n) {
    int t = threadIdx.x;
    if (t < NB) gcur[t] = t * BCAP;
    if (t < 32) {
        ((unsigned*)&y[(size_t)n * 64])[t] = 0u;
        ((unsigned*)&y2[(size_t)n * 64])[t] = 0u;
    }
}

// ---- fused: fill stage A (blocks [0,NC)) + layer-1 MFMA gemm (blocks >= NC).
// CHUNK=3072 keeps LDS at ~18.4KB so gemm blocks co-resident 8/CU.
__global__ __launch_bounds__(256, 8) void k_fill_gemm(
        const int* __restrict__ ei, int E, int NB, int NC,
        int* __restrict__ gcur, unsigned* __restrict__ ebuf,
        const float* __restrict__ X,
        const float* __restrict__ Wa, const float* __restrict__ Wb,
        const float* __restrict__ bias,
        u16* __restrict__ Y, u16* __restrict__ Z, int n) {
    __shared__ unsigned stage[CHUNK];        // 12KB
    __shared__ unsigned char sbkt[CHUNK];    // 3KB
    __shared__ int hist[NBMAX];
    __shared__ int lofs[NBMAX];
    __shared__ int gofs[NBMAX];
    __shared__ int wsum[5];
    int tid = threadIdx.x;

    if (blockIdx.x < (unsigned)NC) {
        // ================= binA body =================
        int c0 = blockIdx.x * CHUNK, cend = min(c0 + CHUNK, E);
        for (int b = tid; b < NB; b += 256) hist[b] = 0;
        __syncthreads();
        for (int e = c0 + tid; e < cend; e += 256)
            atomicAdd(&hist[((const unsigned*)ei)[E + e] >> 9], 1);
        __syncthreads();
        // parallel exclusive scan of hist -> lofs (256 buckets, 1/thread)
        {
            int lane = tid & 63, wid = tid >> 6;
            int v = (tid < NB) ? hist[tid] : 0;
            int inc = v;
#pragma unroll
            for (int off = 1; off < 64; off <<= 1) {
                int t2 = __shfl_up(inc, off, 64);
                if (lane >= off) inc += t2;
            }
            if (lane == 63) wsum[wid] = inc;
            __syncthreads();
            if (tid == 0) {
                int run = 0;
#pragma unroll
                for (int w = 0; w < 4; ++w) { int t3 = wsum[w]; wsum[w] = run; run += t3; }
            }
            __syncthreads();
            if (tid < NB) lofs[tid] = inc - v + wsum[wid];
        }
        __syncthreads();
        for (int b = tid; b < NB; b += 256) {
            gofs[b] = atomicAdd(&gcur[b], hist[b]);   // reserve run in bucket region
            hist[b] = lofs[b];                        // reuse as local cursor
        }
        __syncthreads();
        for (int e = c0 + tid; e < cend; e += 256) {
            unsigned dst = ((const unsigned*)ei)[E + e];
            unsigned src = ((const unsigned*)ei)[e];
            int b = dst >> 9;
            int p = atomicAdd(&hist[b], 1);
            stage[p] = ((dst & 511u) << 17) | src;
            sbkt[p] = (unsigned char)b;
        }
        __syncthreads();
        int m = cend - c0;
        for (int i = tid; i < m; i += 256) {
            int b = sbkt[i];
            int pos = gofs[b] + (i - lofs[b]);
            if (pos < (b + 1) * BCAP) ebuf[pos] = stage[i];   // safety clamp (P~0)
        }
        return;
    }

    // ================= layer-1 gemm body (no LDS use, no barrier) =================
    int n0 = (blockIdx.x - NC) * 64;
    int wid = tid >> 6, lane = tid & 63;
    int lr = lane & 15, lg = lane >> 4;

    const float* Wsrc = (wid < 2) ? Wa : Wb;
    int colL = (wid & 1) * 32 + lr;

    f32x4 acc[4][2];
#pragma unroll
    for (int mt = 0; mt < 4; ++mt)
#pragma unroll
        for (int nt = 0; nt < 2; ++nt) acc[mt][nt] = (f32x4){0.f, 0.f, 0.f, 0.f};

#pragma unroll
    for (int ks = 0; ks < 2; ++ks) {
        int koff = ks * 32 + lg * 8;
        bf16x8 bh[2], bl[2];
#pragma unroll
        for (int nt = 0; nt < 2; ++nt) {
            int c = colL + nt * 16;
            float vb[8];
#pragma unroll
            for (int i = 0; i < 8; ++i) vb[i] = Wsrc[(size_t)(koff + i) * 64 + c];
            split8(vb, bh[nt], bl[nt]);
        }
#pragma unroll
        for (int mt = 0; mt < 4; ++mt) {
            int row = n0 + mt * 16 + lr;
            row = row < n ? row : n - 1;
            float va[8];
            *(float4*)&va[0] = *(const float4*)&X[(size_t)row * 64 + koff];
            *(float4*)&va[4] = *(const float4*)&X[(size_t)row * 64 + koff + 4];
            bf16x8 ah, al;
            split8(va, ah, al);
#pragma unroll
            for (int nt = 0; nt < 2; ++nt) {
                acc[mt][nt] = __builtin_amdgcn_mfma_f32_16x16x32_bf16(ah, bh[nt], acc[mt][nt], 0, 0, 0);
                acc[mt][nt] = __builtin_amdgcn_mfma_f32_16x16x32_bf16(al, bh[nt], acc[mt][nt], 0, 0, 0);
                acc[mt][nt] = __builtin_amdgcn_mfma_f32_16x16x32_bf16(ah, bl[nt], acc[mt][nt], 0, 0, 0);
            }
        }
    }

#pragma unroll
    for (int mt = 0; mt < 4; ++mt) {
#pragma unroll
        for (int nt = 0; nt < 2; ++nt) {
            int col = wid * 32 + nt * 16 + lr;
#pragma unroll
            for (int rg = 0; rg < 4; ++rg) {
                int node = n0 + mt * 16 + lg * 4 + rg;
                if (node < n) {
                    float val = acc[mt][nt][rg];
                    if (col < 64) {
                        Y[(size_t)node * 64 + col] = f2b(val);
                    } else {
                        Z[(size_t)node * 64 + (col - 64)] = f2b(val + bias[col - 64]);
                    }
                }
            }
        }
    }
}

// ---- fill stage B: per-bucket CSR scatter (LDS counters) + cursor + pad ----
__global__ __launch_bounds__(256) void k_binB(const unsigned* __restrict__ ebuf,
                                              const int* __restrict__ gcur,
                                              int* __restrict__ cursor,
                                              int* __restrict__ csr, int n) {
    __shared__ int lcur[512];
    int b = blockIdx.x;
    int tid = threadIdx.x;
    for (int i = tid; i < 512; i += 256) lcur[i] = 0;
    __syncthreads();
    int lo = b * BCAP;
    int m = gcur[b] - lo;
    m = m > BCAP ? BCAP : m;
    int node0 = b << 9;
    for (int i = tid; i < m; i += 256) {
        unsigned v = ebuf[lo + i];
        int ln   = (int)(v >> 17);
        int src  = (int)(v & 0x1FFFFu);
        int slot = atomicAdd(&lcur[ln], 1);
        if (slot < MAXDEG) csr[(size_t)(node0 + ln) * MAXDEG + slot] = src;
    }
    __syncthreads();
    int nb = min(512, n - node0);
    for (int i = tid; i < nb; i += 256) {
        int d = lcur[i];
        cursor[node0 + i] = d;
        int dc = d > MAXDEG ? MAXDEG : d;
        int dcp = (dc + 15) & ~15;
        int* p = &csr[(size_t)(node0 + i) * MAXDEG];
        for (int e = dc; e < dcp; ++e) p[e] = n;
    }
}

// Fused layer-2: gather (y,z -> Hs bf16) + MFMA gemm (Hs -> y2, z2 in-place bf16).
// 512 threads = 8 waves; NL=96 nodes/block. 8-lane groups, uint4 row loads.
__global__ __launch_bounds__(512) void k_l2(const u16* __restrict__ Y,
                                            u16* __restrict__ Z,
                                            const int* __restrict__ deg,
                                            const int* __restrict__ csr,
                                            const float* __restrict__ Wa,
                                            const float* __restrict__ Wb,
                                            const float* __restrict__ bias,
                                            u16* __restrict__ Y2, int n) {
    __shared__ __align__(16) u16 Hs[NL][72];   // 13.8KB; 144B stride -> 2-way only
    __shared__ int qnext;
    int tid = threadIdx.x;
    int n0 = blockIdx.x * NL;
    int wid = tid >> 6, lane = tid & 63;
    int lr = lane & 15, lg = lane >> 4;
    if (tid == 0) qnext = 0;
    __syncthreads();

    // ---- gather phase: dynamic queue; 8-lane groups, uint4 row loads ----
    int q = lane & 7;
    int q8 = q * 8;
    int ldr = lane & 56;     // group leader lane within wave
    for (;;) {
        int slot;
        if (q == 0) slot = atomicAdd(&qnext, 1);
        slot = __shfl(slot, ldr, 64);
        if (slot >= NL) break;
        int node = n0 + slot;
        int d = 1, dcp = 0;
        const int* lst = csr;
        float4 z0 = make_float4(0.f, 0.f, 0.f, 0.f), z1 = z0;
        if (node < n) {
            d = deg[node];
            int dc = d > MAXDEG ? MAXDEG : d;
            dcp = (dc + 15) & ~15;
            lst = &csr[(size_t)node * MAXDEG];
            b2f8(*(const uint4*)&Z[(size_t)node * 64 + q8], z0, z1);
        }
        float4 a0 = make_float4(0.f, 0.f, 0.f, 0.f), a1 = a0;
        for (int e = 0; e < dcp; e += 8) {
            int4 i0 = *(const int4*)&lst[e];
            int4 i1 = *(const int4*)&lst[e + 4];
            uint4 r0 = *(const uint4*)&Y[(size_t)i0.x * 64 + q8];
            uint4 r1 = *(const uint4*)&Y[(size_t)i0.y * 64 + q8];
            uint4 r2 = *(const uint4*)&Y[(size_t)i0.z * 64 + q8];
            uint4 r3 = *(const uint4*)&Y[(size_t)i0.w * 64 + q8];
            uint4 r4 = *(const uint4*)&Y[(size_t)i1.x * 64 + q8];
            uint4 r5 = *(const uint4*)&Y[(size_t)i1.y * 64 + q8];
            uint4 r6 = *(const uint4*)&Y[(size_t)i1.z * 64 + q8];
            uint4 r7 = *(const uint4*)&Y[(size_t)i1.w * 64 + q8];
            bacc8(a0, a1, r0); bacc8(a0, a1, r1); bacc8(a0, a1, r2); bacc8(a0, a1, r3);
            bacc8(a0, a1, r4); bacc8(a0, a1, r5); bacc8(a0, a1, r6); bacc8(a0, a1, r7);
        }
        float inv = 1.0f / (float)(d > 1 ? d : 1);
        float4 v0, v1;
        v0.x = a0.x * inv + z0.x; v0.y = a0.y * inv + z0.y;
        v0.z = a0.z * inv + z0.z; v0.w = a0.w * inv + z0.w;
        v1.x = a1.x * inv + z1.x; v1.y = a1.y * inv + z1.y;
        v1.z = a1.z * inv + z1.z; v1.w = a1.w * inv + z1.w;
        v0.x = v0.x > 0.f ? v0.x : 0.f; v0.y = v0.y > 0.f ? v0.y : 0.f;
        v0.z = v0.z > 0.f ? v0.z : 0.f; v0.w = v0.w > 0.f ? v0.w : 0.f;
        v1.x = v1.x > 0.f ? v1.x : 0.f; v1.y = v1.y > 0.f ? v1.y : 0.f;
        v1.z = v1.z > 0.f ? v1.z : 0.f; v1.w = v1.w > 0.f ? v1.w : 0.f;
        ushort4 h0, h1;
        h0.x = f2b(v0.x); h0.y = f2b(v0.y); h0.z = f2b(v0.z); h0.w = f2b(v0.w);
        h1.x = f2b(v1.x); h1.y = f2b(v1.y); h1.z = f2b(v1.z); h1.w = f2b(v1.w);
        *(ushort4*)&Hs[slot][q8] = h0;
        *(ushort4*)&Hs[slot][q8 + 4] = h1;
    }
    __syncthreads();

    // ---- W fragments (L2-hot; loaded after barrier so gather stays lean) ----
    const float* Wsrc = (wid < 4) ? Wa : Wb;
    int colL = (wid & 3) * 16 + lr;
    bf16x8 bh[2], bl[2];
#pragma unroll
    for (int ks = 0; ks < 2; ++ks) {
        int k0 = ks * 32 + lg * 8;
        float vb[8];
#pragma unroll
        for (int i = 0; i < 8; ++i) vb[i] = Wsrc[(size_t)(k0 + i) * 64 + colL];
        split8(vb, bh[ks], bl[ks]);
    }

    // ---- gemm phase: A direct bf16 from Hs, 16 cols per wave, 2 MFMAs/tile ----
    f32x4 acc[6];
#pragma unroll
    for (int mt = 0; mt < 6; ++mt) acc[mt] = (f32x4){0.f, 0.f, 0.f, 0.f};

#pragma unroll
    for (int ks = 0; ks < 2; ++ks) {
        int koff = ks * 32 + lg * 8;
#pragma unroll
        for (int mt = 0; mt < 6; ++mt) {
            bf16x8 ah = *(const bf16x8*)&Hs[mt * 16 + lr][koff];
            acc[mt] = __builtin_amdgcn_mfma_f32_16x16x32_bf16(ah, bh[ks], acc[mt], 0, 0, 0);
            acc[mt] = __builtin_amdgcn_mfma_f32_16x16x32_bf16(ah, bl[ks], acc[mt], 0, 0, 0);
        }
    }

#pragma unroll
    for (int mt = 0; mt < 6; ++mt) {
#pragma unroll
        for (int rg = 0; rg < 4; ++rg) {
            int node = n0 + mt * 16 + lg * 4 + rg;
            if (node < n) {
                float val = acc[mt][rg];
                if (wid < 4) {
                    Y2[(size_t)node * 64 + colL] = f2b(val);
                } else {
                    Z[(size_t)node * 64 + colL] = f2b(val + bias[colL]);   // own rows only
                }
            }
        }
    }
}

// Layer-2 gather fused with readout dot; 8-lane groups, uint4 row loads.
__global__ __launch_bounds__(256) void k_gather_l2(const u16* __restrict__ Y,
                                                   const u16* __restrict__ Z,
                                                   const int* __restrict__ deg,
                                                   const int* __restrict__ csr,
                                                   const float* __restrict__ Wro,
                                                   float* __restrict__ r, int n) {
    int t = threadIdx.x;
    int grp = t >> 3, q = t & 7;
    int q8 = q * 8;
    int node = blockIdx.x * 32 + grp;
    if (node >= n) return;
    int d = deg[node];
    int dc = d > MAXDEG ? MAXDEG : d;
    int dcp = (dc + 15) & ~15;
    const int* lst = &csr[(size_t)node * MAXDEG];
    float4 z0, z1;
    b2f8(*(const uint4*)&Z[(size_t)node * 64 + q8], z0, z1);
    float4 a0 = make_float4(0.f, 0.f, 0.f, 0.f), a1 = a0;
    for (int e = 0; e < dcp; e += 8) {
        int4 i0 = *(const int4*)&lst[e];
        int4 i1 = *(const int4*)&lst[e + 4];
        uint4 r0 = *(const uint4*)&Y[(size_t)i0.x * 64 + q8];
        uint4 r1 = *(const uint4*)&Y[(size_t)i0.y * 64 + q8];
        uint4 r2 = *(const uint4*)&Y[(size_t)i0.z * 64 + q8];
        uint4 r3 = *(const uint4*)&Y[(size_t)i0.w * 64 + q8];
        uint4 r4 = *(const uint4*)&Y[(size_t)i1.x * 64 + q8];
        uint4 r5 = *(const uint4*)&Y[(size_t)i1.y * 64 + q8];
        uint4 r6 = *(const uint4*)&Y[(size_t)i1.z * 64 + q8];
        uint4 r7 = *(const uint4*)&Y[(size_t)i1.w * 64 + q8];
        bacc8(a0, a1, r0); bacc8(a0, a1, r1); bacc8(a0, a1, r2); bacc8(a0, a1, r3);
        bacc8(a0, a1, r4); bacc8(a0, a1, r5); bacc8(a0, a1, r6); bacc8(a0, a1, r7);
    }
    float inv = 1.0f / (float)(d > 1 ? d : 1);
    float4 v0, v1;
    v0.x = a0.x * inv + z0.x; v0.y = a0.y * inv + z0.y;
    v0.z = a0.z * inv + z0.z; v0.w = a0.w * inv + z0.w;
    v1.x = a1.x * inv + z1.x; v1.y = a1.y * inv + z1.y;
    v1.z = a1.z * inv + z1.z; v1.w = a1.w * inv + z1.w;
    v0.x = v0.x > 0.f ? v0.x : 0.f; v0.y = v0.y > 0.f ? v0.y : 0.f;
    v0.z = v0.z > 0.f ? v0.z : 0.f; v0.w = v0.w > 0.f ? v0.w : 0.f;
    v1.x = v1.x > 0.f ? v1.x : 0.f; v1.y = v1.y > 0.f ? v1.y : 0.f;
    v1.z = v1.z > 0.f ? v1.z : 0.f; v1.w = v1.w > 0.f ? v1.w : 0.f;
    float4 w0 = *(const float4*)&Wro[q8];
    float4 w1 = *(const float4*)&Wro[q8 + 4];
    float s = v0.x * w0.x + v0.y * w0.y + v0.z * w0.z + v0.w * w0.w
            + v1.x * w1.x + v1.y * w1.y + v1.z * w1.z + v1.w * w1.w;
    s += __shfl_xor(s, 1, 8);
    s += __shfl_xor(s, 2, 8);
    s += __shfl_xor(s, 4, 8);
    if (q == 0) r[node] = s;
}

// One block per graph: mean of r over the graph's contiguous node range + bro.
__global__ __launch_bounds__(256) void k_pool(const float* __restrict__ r,
                                              const int* __restrict__ batch,
                                              const float* __restrict__ bro,
                                              float* __restrict__ out, int n) {
    __shared__ float wsum[4];
    int gidx = blockIdx.x;
    int tid = threadIdx.x;
    int lo = 0, hi = n;
    while (lo < hi) { int m = (lo + hi) >> 1; if (batch[m] < gidx) lo = m + 1; else hi = m; }
    int lb = lo;
    lo = 0; hi = n;
    while (lo < hi) { int m = (lo + hi) >> 1; if (batch[m] < gidx + 1) lo = m + 1; else hi = m; }
    int ub = lo;
    float s = 0.f;
    for (int i = lb + tid; i < ub; i += 256) s += r[i];
#pragma unroll
    for (int off = 32; off; off >>= 1) s += __shfl_xor(s, off, 64);
    if ((tid & 63) == 0) wsum[tid >> 6] = s;
    __syncthreads();
    if (tid == 0) {
        float tot = wsum[0] + wsum[1] + wsum[2] + wsum[3];
        int c = ub - lb;
        out[gidx] = tot / (float)(c > 1 ? c : 1) + bro[0];
    }
}

extern "C" void kernel_launch(void* const* d_in, const int* in_sizes, int n_in,
                              void* d_out, int out_size, void* d_ws, size_t ws_size,
                              hipStream_t stream) {
    const float* x   = (const float*)d_in[0];
    const float* Wl1 = (const float*)d_in[1];
    const float* bl1 = (const float*)d_in[2];
    const float* Wr1 = (const float*)d_in[3];
    const float* Wl2 = (const float*)d_in[4];
    const float* bl2 = (const float*)d_in[5];
    const float* Wr2 = (const float*)d_in[6];
    const float* Wro = (const float*)d_in[7];
    const float* bro = (const float*)d_in[8];
    const int* ei    = (const int*)d_in[9];
    const int* batch = (const int*)d_in[10];

    int N = in_sizes[0] / 64;
    int E = in_sizes[9] / 2;
    int G = out_size;
    int NB = (N + 511) >> 9;              // buckets of 512 nodes
    int NC = (E + CHUNK - 1) / CHUNK;     // chunks

    char* ws = (char*)d_ws;
    size_t off = 0;
    auto carve = [&](size_t bytes) {
        void* p = ws + off;
        off += (bytes + 255) & ~(size_t)255;
        return p;
    };
    int*      cursor = (int*)carve((size_t)N * 4);
    int*      csr    = (int*)carve((size_t)N * MAXDEG * 4);
    u16*      y      = (u16*)carve((size_t)(N + 1) * 64 * 2);   // layer-1 bf16 rows + sentinel
    u16*      y2     = (u16*)carve((size_t)(N + 1) * 64 * 2);   // layer-2 bf16 rows + sentinel
    u16*      z      = (u16*)carve((size_t)N * 64 * 2);         // z bf16 (layer1, then layer2 in-place)
    float*    r      = (float*)carve((size_t)N * 4);
    int*      gcur   = (int*)carve((size_t)NB * 4);
    unsigned* ebuf   = (unsigned*)carve((size_t)NB * BCAP * 4);

    int gemmBlocks = (N + 63) / 64;
    k_init<<<1, 256, 0, stream>>>(gcur, NB, y, y2, N);
    k_fill_gemm<<<NC + gemmBlocks, 256, 0, stream>>>(ei, E, NB, NC, gcur, ebuf,
                                                     x, Wl1, Wr1, bl1, y, z, N);
    k_binB<<<NB, 256, 0, stream>>>(ebuf, gcur, cursor, csr, N);
    k_l2<<<(N + NL - 1) / NL, 512, 0, stream>>>(y, z, cursor, csr, Wl2, Wr2, bl2, y2, N);
    k_gather_l2<<<(N + 31) / 32, 256, 0, stream>>>(y2, z, cursor, csr, Wro, r, N);
    k_pool<<<G, 256, 0, stream>>>(r, batch, bro, (float*)d_out, N);
}

// Round 19
// 154.209 us; speedup vs baseline: 1.0573x; 1.0573x over previous
//
#include <hip/hip_runtime.h>

#define MAXDEG 64
#define CHUNK 6144
#define NBMAX 256   // buckets = ceil(N/512); N<=131072 (src must fit 17 bits)
#define BCAP 10240  // per-bucket ebuf capacity (mean 8192, sd ~90 -> +22 sigma)
#define NL 96       // k_l2 nodes per block (grid ~1042 -> 32 waves/CU)

typedef unsigned short u16;
typedef __attribute__((ext_vector_type(8))) short bf16x8;
typedef __attribute__((ext_vector_type(4))) float f32x4;

__device__ __forceinline__ u16 f2b(float f) {   // fp32 -> bf16 rne
    unsigned u = __float_as_uint(f);
    u += 0x7fffu + ((u >> 16) & 1u);
    return (u16)(u >> 16);
}

// Split 8 fp32 -> bf16x8 hi (truncate) + bf16x8 lo (trunc of exact remainder).
__device__ __forceinline__ void split8(const float* v, bf16x8& hi, bf16x8& lo) {
    unsigned hw[4], lw[4];
#pragma unroll
    for (int p = 0; p < 4; ++p) {
        unsigned u0 = __float_as_uint(v[2 * p]);
        unsigned u1 = __float_as_uint(v[2 * p + 1]);
        float l0 = v[2 * p]     - __uint_as_float(u0 & 0xffff0000u);
        float l1 = v[2 * p + 1] - __uint_as_float(u1 & 0xffff0000u);
        hw[p] = (u0 >> 16) | (u1 & 0xffff0000u);
        lw[p] = (__float_as_uint(l0) >> 16) | (__float_as_uint(l1) & 0xffff0000u);
    }
    hi = *reinterpret_cast<bf16x8*>(hw);
    lo = *reinterpret_cast<bf16x8*>(lw);
}

// acc(2x float4) += 8 packed bf16 (uint4)
__device__ __forceinline__ void bacc8(float4& a0, float4& a1, uint4 w) {
    a0.x += __uint_as_float(w.x << 16);
    a0.y += __uint_as_float(w.x & 0xffff0000u);
    a0.z += __uint_as_float(w.y << 16);
    a0.w += __uint_as_float(w.y & 0xffff0000u);
    a1.x += __uint_as_float(w.z << 16);
    a1.y += __uint_as_float(w.z & 0xffff0000u);
    a1.z += __uint_as_float(w.w << 16);
    a1.w += __uint_as_float(w.w & 0xffff0000u);
}

// unpack 8 packed bf16 -> 2x float4
__device__ __forceinline__ void b2f8(uint4 w, float4& r0, float4& r1) {
    r0.x = __uint_as_float(w.x << 16);
    r0.y = __uint_as_float(w.x & 0xffff0000u);
    r0.z = __uint_as_float(w.y << 16);
    r0.w = __uint_as_float(w.y & 0xffff0000u);
    r1.x = __uint_as_float(w.z << 16);
    r1.y = __uint_as_float(w.z & 0xffff0000u);
    r1.z = __uint_as_float(w.w << 16);
    r1.w = __uint_as_float(w.w & 0xffff0000u);
}

// ---- init: bucket cursors to region bases; zero sentinel rows ----
__global__ void k_init(int* __restrict__ gcur, int NB,
                       u16* __restrict__ y, u16* __restrict__ y2, int n) {
    int t = threadIdx.x;
    if (t < NB) gcur[t] = t * BCAP;
    if (t < 32) {
        ((unsigned*)&y[(size_t)n * 64])[t] = 0u;
        ((unsigned*)&y2[(size_t)n * 64])[t] = 0u;
    }
}

// ---- fused: fill stage A (blocks [0,NC)) + layer-1 MFMA gemm (blocks >= NC).
__global__ __launch_bounds__(256, 8) void k_fill_gemm(
        const int* __restrict__ ei, int E, int NB, int NC,
        int* __restrict__ gcur, unsigned* __restrict__ ebuf,
        const float* __restrict__ X,
        const float* __restrict__ Wa, const float* __restrict__ Wb,
        const float* __restrict__ bias,
        u16* __restrict__ Y, u16* __restrict__ Z, int n) {
    __shared__ unsigned stage[CHUNK];        // 24KB
    __shared__ unsigned char sbkt[CHUNK];    // 6KB
    __shared__ int hist[NBMAX];
    __shared__ int lofs[NBMAX];
    __shared__ int gofs[NBMAX];
    __shared__ int wsum[5];
    int tid = threadIdx.x;

    if (blockIdx.x < (unsigned)NC) {
        // ================= binA body =================
        int c0 = blockIdx.x * CHUNK, cend = min(c0 + CHUNK, E);
        for (int b = tid; b < NB; b += 256) hist[b] = 0;
        __syncthreads();
        for (int e = c0 + tid; e < cend; e += 256)
            atomicAdd(&hist[((const unsigned*)ei)[E + e] >> 9], 1);
        __syncthreads();
        // parallel exclusive scan of hist -> lofs (256 buckets, 1/thread)
        {
            int lane = tid & 63, wid = tid >> 6;
            int v = (tid < NB) ? hist[tid] : 0;
            int inc = v;
#pragma unroll
            for (int off = 1; off < 64; off <<= 1) {
                int t2 = __shfl_up(inc, off, 64);
                if (lane >= off) inc += t2;
            }
            if (lane == 63) wsum[wid] = inc;
            __syncthreads();
            if (tid == 0) {
                int run = 0;
#pragma unroll
                for (int w = 0; w < 4; ++w) { int t3 = wsum[w]; wsum[w] = run; run += t3; }
            }
            __syncthreads();
            if (tid < NB) lofs[tid] = inc - v + wsum[wid];
        }
        __syncthreads();
        for (int b = tid; b < NB; b += 256) {
            gofs[b] = atomicAdd(&gcur[b], hist[b]);   // reserve run in bucket region
            hist[b] = lofs[b];                        // reuse as local cursor
        }
        __syncthreads();
        for (int e = c0 + tid; e < cend; e += 256) {
            unsigned dst = ((const unsigned*)ei)[E + e];
            unsigned src = ((const unsigned*)ei)[e];
            int b = dst >> 9;
            int p = atomicAdd(&hist[b], 1);
            stage[p] = ((dst & 511u) << 17) | src;
            sbkt[p] = (unsigned char)b;
        }
        __syncthreads();
        int m = cend - c0;
        for (int i = tid; i < m; i += 256) {
            int b = sbkt[i];
            int pos = gofs[b] + (i - lofs[b]);
            if (pos < (b + 1) * BCAP) ebuf[pos] = stage[i];   // safety clamp (P~0)
        }
        return;
    }

    // ================= layer-1 gemm body (no LDS use, no barrier) =================
    int n0 = (blockIdx.x - NC) * 64;
    int wid = tid >> 6, lane = tid & 63;
    int lr = lane & 15, lg = lane >> 4;

    const float* Wsrc = (wid < 2) ? Wa : Wb;
    int colL = (wid & 1) * 32 + lr;

    f32x4 acc[4][2];
#pragma unroll
    for (int mt = 0; mt < 4; ++mt)
#pragma unroll
        for (int nt = 0; nt < 2; ++nt) acc[mt][nt] = (f32x4){0.f, 0.f, 0.f, 0.f};

#pragma unroll
    for (int ks = 0; ks < 2; ++ks) {
        int koff = ks * 32 + lg * 8;
        bf16x8 bh[2], bl[2];
#pragma unroll
        for (int nt = 0; nt < 2; ++nt) {
            int c = colL + nt * 16;
            float vb[8];
#pragma unroll
            for (int i = 0; i < 8; ++i) vb[i] = Wsrc[(size_t)(koff + i) * 64 + c];
            split8(vb, bh[nt], bl[nt]);
        }
#pragma unroll
        for (int mt = 0; mt < 4; ++mt) {
            int row = n0 + mt * 16 + lr;
            row = row < n ? row : n - 1;
            float va[8];
            *(float4*)&va[0] = *(const float4*)&X[(size_t)row * 64 + koff];
            *(float4*)&va[4] = *(const float4*)&X[(size_t)row * 64 + koff + 4];
            bf16x8 ah, al;
            split8(va, ah, al);
#pragma unroll
            for (int nt = 0; nt < 2; ++nt) {
                acc[mt][nt] = __builtin_amdgcn_mfma_f32_16x16x32_bf16(ah, bh[nt], acc[mt][nt], 0, 0, 0);
                acc[mt][nt] = __builtin_amdgcn_mfma_f32_16x16x32_bf16(al, bh[nt], acc[mt][nt], 0, 0, 0);
                acc[mt][nt] = __builtin_amdgcn_mfma_f32_16x16x32_bf16(ah, bl[nt], acc[mt][nt], 0, 0, 0);
            }
        }
    }

#pragma unroll
    for (int mt = 0; mt < 4; ++mt) {
#pragma unroll
        for (int nt = 0; nt < 2; ++nt) {
            int col = wid * 32 + nt * 16 + lr;
#pragma unroll
            for (int rg = 0; rg < 4; ++rg) {
                int node = n0 + mt * 16 + lg * 4 + rg;
                if (node < n) {
                    float val = acc[mt][nt][rg];
                    if (col < 64) {
                        Y[(size_t)node * 64 + col] = f2b(val);
                    } else {
                        Z[(size_t)node * 64 + (col - 64)] = f2b(val + bias[col - 64]);
                    }
                }
            }
        }
    }
}

// ---- fill stage B: per-bucket CSR scatter (LDS counters) + cursor + pad ----
__global__ __launch_bounds__(256) void k_binB(const unsigned* __restrict__ ebuf,
                                              const int* __restrict__ gcur,
                                              int* __restrict__ cursor,
                                              int* __restrict__ csr, int n) {
    __shared__ int lcur[512];
    int b = blockIdx.x;
    int tid = threadIdx.x;
    for (int i = tid; i < 512; i += 256) lcur[i] = 0;
    __syncthreads();
    int lo = b * BCAP;
    int m = gcur[b] - lo;
    m = m > BCAP ? BCAP : m;
    int node0 = b << 9;
    for (int i = tid; i < m; i += 256) {
        unsigned v = ebuf[lo + i];
        int ln   = (int)(v >> 17);
        int src  = (int)(v & 0x1FFFFu);
        int slot = atomicAdd(&lcur[ln], 1);
        if (slot < MAXDEG) csr[(size_t)(node0 + ln) * MAXDEG + slot] = src;
    }
    __syncthreads();
    int nb = min(512, n - node0);
    for (int i = tid; i < nb; i += 256) {
        int d = lcur[i];
        cursor[node0 + i] = d;
        int dc = d > MAXDEG ? MAXDEG : d;
        int dcp = (dc + 15) & ~15;
        int* p = &csr[(size_t)(node0 + i) * MAXDEG];
        for (int e = dc; e < dcp; ++e) p[e] = n;
    }
}

// Fused layer-2: gather (y,z -> Hs bf16) + MFMA gemm (Hs -> y2, z2 in-place bf16).
// 512 threads = 8 waves; NL=96 nodes/block. 8-lane groups, uint4 row loads.
__global__ __launch_bounds__(512) void k_l2(const u16* __restrict__ Y,
                                            u16* __restrict__ Z,
                                            const int* __restrict__ deg,
                                            const int* __restrict__ csr,
                                            const float* __restrict__ Wa,
                                            const float* __restrict__ Wb,
                                            const float* __restrict__ bias,
                                            u16* __restrict__ Y2, int n) {
    __shared__ __align__(16) u16 Hs[NL][72];   // 13.8KB; 144B stride -> 2-way only
    __shared__ int qnext;
    int tid = threadIdx.x;
    int n0 = blockIdx.x * NL;
    int wid = tid >> 6, lane = tid & 63;
    int lr = lane & 15, lg = lane >> 4;
    if (tid == 0) qnext = 0;
    __syncthreads();

    // ---- gather phase: dynamic queue; 8-lane groups, uint4 row loads ----
    int q = lane & 7;
    int q8 = q * 8;
    int ldr = lane & 56;     // group leader lane within wave
    for (;;) {
        int slot;
        if (q == 0) slot = atomicAdd(&qnext, 1);
        slot = __shfl(slot, ldr, 64);
        if (slot >= NL) break;
        int node = n0 + slot;
        int d = 1, dcp = 0;
        const int* lst = csr;
        float4 z0 = make_float4(0.f, 0.f, 0.f, 0.f), z1 = z0;
        if (node < n) {
            d = deg[node];
            int dc = d > MAXDEG ? MAXDEG : d;
            dcp = (dc + 15) & ~15;
            lst = &csr[(size_t)node * MAXDEG];
            b2f8(*(const uint4*)&Z[(size_t)node * 64 + q8], z0, z1);
        }
        float4 a0 = make_float4(0.f, 0.f, 0.f, 0.f), a1 = a0;
        for (int e = 0; e < dcp; e += 8) {
            int4 i0 = *(const int4*)&lst[e];
            int4 i1 = *(const int4*)&lst[e + 4];
            uint4 r0 = *(const uint4*)&Y[(size_t)i0.x * 64 + q8];
            uint4 r1 = *(const uint4*)&Y[(size_t)i0.y * 64 + q8];
            uint4 r2 = *(const uint4*)&Y[(size_t)i0.z * 64 + q8];
            uint4 r3 = *(const uint4*)&Y[(size_t)i0.w * 64 + q8];
            uint4 r4 = *(const uint4*)&Y[(size_t)i1.x * 64 + q8];
            uint4 r5 = *(const uint4*)&Y[(size_t)i1.y * 64 + q8];
            uint4 r6 = *(const uint4*)&Y[(size_t)i1.z * 64 + q8];
            uint4 r7 = *(const uint4*)&Y[(size_t)i1.w * 64 + q8];
            bacc8(a0, a1, r0); bacc8(a0, a1, r1); bacc8(a0, a1, r2); bacc8(a0, a1, r3);
            bacc8(a0, a1, r4); bacc8(a0, a1, r5); bacc8(a0, a1, r6); bacc8(a0, a1, r7);
        }
        float inv = 1.0f / (float)(d > 1 ? d : 1);
        float4 v0, v1;
        v0.x = a0.x * inv + z0.x; v0.y = a0.y * inv + z0.y;
        v0.z = a0.z * inv + z0.z; v0.w = a0.w * inv + z0.w;
        v1.x = a1.x * inv + z1.x; v1.y = a1.y * inv + z1.y;
        v1.z = a1.z * inv + z1.z; v1.w = a1.w * inv + z1.w;
        v0.x = v0.x > 0.f ? v0.x : 0.f; v0.y = v0.y > 0.f ? v0.y : 0.f;
        v0.z = v0.z > 0.f ? v0.z : 0.f; v0.w = v0.w > 0.f ? v0.w : 0.f;
        v1.x = v1.x > 0.f ? v1.x : 0.f; v1.y = v1.y > 0.f ? v1.y : 0.f;
        v1.z = v1.z > 0.f ? v1.z : 0.f; v1.w = v1.w > 0.f ? v1.w : 0.f;
        ushort4 h0, h1;
        h0.x = f2b(v0.x); h0.y = f2b(v0.y); h0.z = f2b(v0.z); h0.w = f2b(v0.w);
        h1.x = f2b(v1.x); h1.y = f2b(v1.y); h1.z = f2b(v1.z); h1.w = f2b(v1.w);
        *(ushort4*)&Hs[slot][q8] = h0;
        *(ushort4*)&Hs[slot][q8 + 4] = h1;
    }
    __syncthreads();

    // ---- W fragments (L2-hot; loaded after barrier so gather stays lean) ----
    const float* Wsrc = (wid < 4) ? Wa : Wb;
    int colL = (wid & 3) * 16 + lr;
    bf16x8 bh[2], bl[2];
#pragma unroll
    for (int ks = 0; ks < 2; ++ks) {
        int k0 = ks * 32 + lg * 8;
        float vb[8];
#pragma unroll
        for (int i = 0; i < 8; ++i) vb[i] = Wsrc[(size_t)(k0 + i) * 64 + colL];
        split8(vb, bh[ks], bl[ks]);
    }

    // ---- gemm phase: A direct bf16 from Hs, 16 cols per wave, 2 MFMAs/tile ----
    f32x4 acc[6];
#pragma unroll
    for (int mt = 0; mt < 6; ++mt) acc[mt] = (f32x4){0.f, 0.f, 0.f, 0.f};

#pragma unroll
    for (int ks = 0; ks < 2; ++ks) {
        int koff = ks * 32 + lg * 8;
#pragma unroll
        for (int mt = 0; mt < 6; ++mt) {
            bf16x8 ah = *(const bf16x8*)&Hs[mt * 16 + lr][koff];
            acc[mt] = __builtin_amdgcn_mfma_f32_16x16x32_bf16(ah, bh[ks], acc[mt], 0, 0, 0);
            acc[mt] = __builtin_amdgcn_mfma_f32_16x16x32_bf16(ah, bl[ks], acc[mt], 0, 0, 0);
        }
    }

#pragma unroll
    for (int mt = 0; mt < 6; ++mt) {
#pragma unroll
        for (int rg = 0; rg < 4; ++rg) {
            int node = n0 + mt * 16 + lg * 4 + rg;
            if (node < n) {
                float val = acc[mt][rg];
                if (wid < 4) {
                    Y2[(size_t)node * 64 + colL] = f2b(val);
                } else {
                    Z[(size_t)node * 64 + colL] = f2b(val + bias[colL]);   // own rows only
                }
            }
        }
    }
}

// Layer-2 gather fused with readout dot; 8-lane groups, uint4 row loads.
__global__ __launch_bounds__(256) void k_gather_l2(const u16* __restrict__ Y,
                                                   const u16* __restrict__ Z,
                                                   const int* __restrict__ deg,
                                                   const int* __restrict__ csr,
                                                   const float* __restrict__ Wro,
                                                   float* __restrict__ r, int n) {
    int t = threadIdx.x;
    int grp = t >> 3, q = t & 7;
    int q8 = q * 8;
    int node = blockIdx.x * 32 + grp;
    if (node >= n) return;
    int d = deg[node];
    int dc = d > MAXDEG ? MAXDEG : d;
    int dcp = (dc + 15) & ~15;
    const int* lst = &csr[(size_t)node * MAXDEG];
    float4 z0, z1;
    b2f8(*(const uint4*)&Z[(size_t)node * 64 + q8], z0, z1);
    float4 a0 = make_float4(0.f, 0.f, 0.f, 0.f), a1 = a0;
    for (int e = 0; e < dcp; e += 8) {
        int4 i0 = *(const int4*)&lst[e];
        int4 i1 = *(const int4*)&lst[e + 4];
        uint4 r0 = *(const uint4*)&Y[(size_t)i0.x * 64 + q8];
        uint4 r1 = *(const uint4*)&Y[(size_t)i0.y * 64 + q8];
        uint4 r2 = *(const uint4*)&Y[(size_t)i0.z * 64 + q8];
        uint4 r3 = *(const uint4*)&Y[(size_t)i0.w * 64 + q8];
        uint4 r4 = *(const uint4*)&Y[(size_t)i1.x * 64 + q8];
        uint4 r5 = *(const uint4*)&Y[(size_t)i1.y * 64 + q8];
        uint4 r6 = *(const uint4*)&Y[(size_t)i1.z * 64 + q8];
        uint4 r7 = *(const uint4*)&Y[(size_t)i1.w * 64 + q8];
        bacc8(a0, a1, r0); bacc8(a0, a1, r1); bacc8(a0, a1, r2); bacc8(a0, a1, r3);
        bacc8(a0, a1, r4); bacc8(a0, a1, r5); bacc8(a0, a1, r6); bacc8(a0, a1, r7);
    }
    float inv = 1.0f / (float)(d > 1 ? d : 1);
    float4 v0, v1;
    v0.x = a0.x * inv + z0.x; v0.y = a0.y * inv + z0.y;
    v0.z = a0.z * inv + z0.z; v0.w = a0.w * inv + z0.w;
    v1.x = a1.x * inv + z1.x; v1.y = a1.y * inv + z1.y;
    v1.z = a1.z * inv + z1.z; v1.w = a1.w * inv + z1.w;
    v0.x = v0.x > 0.f ? v0.x : 0.f; v0.y = v0.y > 0.f ? v0.y : 0.f;
    v0.z = v0.z > 0.f ? v0.z : 0.f; v0.w = v0.w > 0.f ? v0.w : 0.f;
    v1.x = v1.x > 0.f ? v1.x : 0.f; v1.y = v1.y > 0.f ? v1.y : 0.f;
    v1.z = v1.z > 0.f ? v1.z : 0.f; v1.w = v1.w > 0.f ? v1.w : 0.f;
    float4 w0 = *(const float4*)&Wro[q8];
    float4 w1 = *(const float4*)&Wro[q8 + 4];
    float s = v0.x * w0.x + v0.y * w0.y + v0.z * w0.z + v0.w * w0.w
            + v1.x * w1.x + v1.y * w1.y + v1.z * w1.z + v1.w * w1.w;
    s += __shfl_xor(s, 1, 8);
    s += __shfl_xor(s, 2, 8);
    s += __shfl_xor(s, 4, 8);
    if (q == 0) r[node] = s;
}

// One block per graph: mean of r over the graph's contiguous node range + bro.
__global__ __launch_bounds__(256) void k_pool(const float* __restrict__ r,
                                              const int* __restrict__ batch,
                                              const float* __restrict__ bro,
                                              float* __restrict__ out, int n) {
    __shared__ float wsum[4];
    int gidx = blockIdx.x;
    int tid = threadIdx.x;
    int lo = 0, hi = n;
    while (lo < hi) { int m = (lo + hi) >> 1; if (batch[m] < gidx) lo = m + 1; else hi = m; }
    int lb = lo;
    lo = 0; hi = n;
    while (lo < hi) { int m = (lo + hi) >> 1; if (batch[m] < gidx + 1) lo = m + 1; else hi = m; }
    int ub = lo;
    float s = 0.f;
    for (int i = lb + tid; i < ub; i += 256) s += r[i];
#pragma unroll
    for (int off = 32; off; off >>= 1) s += __shfl_xor(s, off, 64);
    if ((tid & 63) == 0) wsum[tid >> 6] = s;
    __syncthreads();
    if (tid == 0) {
        float tot = wsum[0] + wsum[1] + wsum[2] + wsum[3];
        int c = ub - lb;
        out[gidx] = tot / (float)(c > 1 ? c : 1) + bro[0];
    }
}

extern "C" void kernel_launch(void* const* d_in, const int* in_sizes, int n_in,
                              void* d_out, int out_size, void* d_ws, size_t ws_size,
                              hipStream_t stream) {
    const float* x   = (const float*)d_in[0];
    const float* Wl1 = (const float*)d_in[1];
    const float* bl1 = (const float*)d_in[2];
    const float* Wr1 = (const float*)d_in[3];
    const float* Wl2 = (const float*)d_in[4];
    const float* bl2 = (const float*)d_in[5];
    const float* Wr2 = (const float*)d_in[6];
    const float* Wro = (const float*)d_in[7];
    const float* bro = (const float*)d_in[8];
    const int* ei    = (const int*)d_in[9];
    const int* batch = (const int*)d_in[10];

    int N = in_sizes[0] / 64;
    int E = in_sizes[9] / 2;
    int G = out_size;
    int NB = (N + 511) >> 9;              // buckets of 512 nodes
    int NC = (E + CHUNK - 1) / CHUNK;     // chunks

    char* ws = (char*)d_ws;
    size_t off = 0;
    auto carve = [&](size_t bytes) {
        void* p = ws + off;
        off += (bytes + 255) & ~(size_t)255;
        return p;
    };
    int*      cursor = (int*)carve((size_t)N * 4);
    int*      csr    = (int*)carve((size_t)N * MAXDEG * 4);
    u16*      y      = (u16*)carve((size_t)(N + 1) * 64 * 2);   // layer-1 bf16 rows + sentinel
    u16*      y2     = (u16*)carve((size_t)(N + 1) * 64 * 2);   // layer-2 bf16 rows + sentinel
    u16*      z      = (u16*)carve((size_t)N * 64 * 2);         // z bf16 (layer1, then layer2 in-place)
    float*    r      = (float*)carve((size_t)N * 4);
    int*      gcur   = (int*)carve((size_t)NB * 4);
    unsigned* ebuf   = (unsigned*)carve((size_t)NB * BCAP * 4);

    int gemmBlocks = (N + 63) / 64;
    k_init<<<1, 256, 0, stream>>>(gcur, NB, y, y2, N);
    k_fill_gemm<<<NC + gemmBlocks, 256, 0, stream>>>(ei, E, NB, NC, gcur, ebuf,
                                                     x, Wl1, Wr1, bl1, y, z, N);
    k_binB<<<NB, 256, 0, stream>>>(ebuf, gcur, cursor, csr, N);
    k_l2<<<(N + NL - 1) / NL, 512, 0, stream>>>(y, z, cursor, csr, Wl2, Wr2, bl2, y2, N);
    k_gather_l2<<<(N + 31) / 32, 256, 0, stream>>>(y2, z, cursor, csr, Wro, r, N);
    k_pool<<<G, 256, 0, stream>>>(r, batch, bro, (float*)d_out, N);
}